// Round 10
// baseline (341.311 us; speedup 1.0000x reference)
//
#include <hip/hip_runtime.h>
#include <math.h>

// Problem constants (fixed by reference)
constexpr int B_  = 16;
constexpr int NP_ = 512;
constexpr int NO_ = 512;
constexpr int T_  = 2048;
constexpr int NF_ = 8;
constexpr int HS_ = 256;
constexpr int TR_ = 2030;   // T - (DELAY + SKIP*(NF-1))
constexpr int TO_ = 2044;   // T - DELAY
constexpr int OPLD_ = 2048; // padded row stride for proj outputs
constexpr float EPS_ = 1e-5f;

typedef short bf16x8 __attribute__((ext_vector_type(8)));
typedef float f32x16 __attribute__((ext_vector_type(16)));

__device__ __forceinline__ unsigned short f2bf(float f) {
  union { float f; unsigned int u; } v; v.f = f;
  unsigned int r = v.u + 0x7fffu + ((v.u >> 16) & 1u);  // RNE
  return (unsigned short)(r >> 16);
}
__device__ __forceinline__ float bf2f(unsigned short u) {
  union { unsigned int u; float f; } v; v.u = ((unsigned int)u) << 16;
  return v.f;
}

// global -> LDS direct (16B/lane). LDS dest = wave-uniform base + lane*16.
typedef const __attribute__((address_space(1))) unsigned int* gas_u32;
typedef __attribute__((address_space(3))) unsigned int* las_u32;
__device__ __forceinline__ void gl16(const void* g, void* l) {
  __builtin_amdgcn_global_load_lds((gas_u32)g, (las_u32)l, 16, 0, 0);
}

// Tile geometry: [R][64] bf16 tiles, 128B rows. LDS chunk index for (row r,
// col-chunk c8) is r*8 + (c8 ^ (r&7)).  Staging: lane handling linear chunk q
// covers row r=q>>3, source col-chunk (q&7)^(r&7) -> coalesced 128B/8-lanes.
// Fragment read (row rr, k-chunk k8): elem offset rr*64 + ((k8^(rr&7))<<3).

// ---------------------------------------------------------------------------
// Transpose + cast (merged): z<16 -> predictor->pred_t (b=z); z>=16 ->
// to_order->too_t (b=z-16). in f32 [b][512][2048] -> out bf16 [b][2048][512]
// ---------------------------------------------------------------------------
__global__ __launch_bounds__(256) void transpose_cvt(
    const float* __restrict__ inA, unsigned short* __restrict__ outA,
    const float* __restrict__ inB, unsigned short* __restrict__ outB) {
  __shared__ float tile[64][65];
  const int c0 = blockIdx.x * 64;  // t dim
  const int r0 = blockIdx.y * 64;  // p dim
  const int z  = blockIdx.z;
  const int b  = z & 15;
  const float* ib = ((z < 16) ? inA : inB) + (size_t)b * 512 * 2048;
  unsigned short* ob = ((z < 16) ? outA : outB) + (size_t)b * 2048 * 512;
  for (int i = threadIdx.x; i < 64 * 16; i += 256) {
    const int r = i >> 4, c4 = (i & 15) * 4;
    float4 v = *(const float4*)(ib + (size_t)(r0 + r) * 2048 + c0 + c4);
    tile[r][c4 + 0] = v.x; tile[r][c4 + 1] = v.y;
    tile[r][c4 + 2] = v.z; tile[r][c4 + 3] = v.w;
  }
  __syncthreads();
  for (int i = threadIdx.x; i < 64 * 8; i += 256) {
    const int c = i >> 3, r8 = (i & 7) * 8;
    unsigned int pk[4];
    #pragma unroll
    for (int e = 0; e < 4; ++e)
      pk[e] = (unsigned int)f2bf(tile[r8 + 2 * e][c]) |
              ((unsigned int)f2bf(tile[r8 + 2 * e + 1][c]) << 16);
    *(uint4*)(ob + (size_t)(c0 + c) * 512 + r0 + r8) = *(uint4*)pk;
  }
}

// Elementwise f32 -> bf16, three tensors range-dispatched in one launch.
__global__ __launch_bounds__(256) void cvt_all(
    const float* __restrict__ tri, unsigned short* __restrict__ trib,
    const float* __restrict__ wo, unsigned short* __restrict__ wob,
    const float* __restrict__ wp, unsigned short* __restrict__ wpb) {
  const int n1 = NF_ * NO_ * NP_, n2 = HS_ * 512;
  int i = (blockIdx.x * 256 + threadIdx.x) * 4;
  const float* in; unsigned short* out;
  if (i < n1)           { in = tri; out = trib; }
  else if (i < n1 + n2) { i -= n1; in = wo; out = wob; }
  else                  { i -= n1 + n2; in = wp; out = wpb; }
  float4 v = *(const float4*)(in + i);
  ushort4 o; o.x = f2bf(v.x); o.y = f2bf(v.y); o.z = f2bf(v.z); o.w = f2bf(v.w);
  *(ushort4*)(out + i) = o;
}

// ---------------------------------------------------------------------------
// MERGED proj + inner kernel. grid (16, 8, 16), 2 blocks/CU (LDS 76KB):
//   y in [0,4): inner path, kf0 = y*2 (v7: m-split Phase A, 4 reads/4 MFMAs).
//   y in [4,8): proj path, yy=y-4: sel=yy>>1 (0: o-proj from too_t,
//     1: p-proj from pred_t), m0=(yy&1)*128.
// The two paths are data-independent; co-residency (1 inner + 1 proj per CU)
// overlaps proj's staging drains with inner's MFMA issue (m114 overlap).
// ---------------------------------------------------------------------------
__global__ __launch_bounds__(256, 2) void proj_inner_mfma(
    const unsigned short* __restrict__ pred_t,  // [B][T][NP] bf16
    const unsigned short* __restrict__ too_t,   // [B][T][NO] bf16
    const unsigned short* __restrict__ tri_bf,  // [NF][NO][NP] bf16
    float* __restrict__ inner,                  // [B][NF][NF][TR] f32
    const unsigned short* __restrict__ Wo, const unsigned short* __restrict__ Wp,
    const float* __restrict__ biasO, const float* __restrict__ biasP,
    unsigned short* __restrict__ outO, unsigned short* __restrict__ outP) {
  __shared__ char smem[77824];
  const int tid = threadIdx.x;
  const int l = tid & 63, wv = tid >> 6;
  const int h = l >> 5, tl = l & 31;
  const int t0 = blockIdx.x * 128;
  const int b  = blockIdx.z;

  if (blockIdx.y >= 4) {
    // ====================== proj path ======================
    char* const Ab[2] = { smem, smem + 16384 };
    char* const Bb[2] = { smem + 32768, smem + 49152 };
    const int yy = blockIdx.y - 4;
    const int sel = yy >> 1;
    const unsigned short* Wbf = sel ? Wp : Wo;
    const unsigned short* Xt  = sel ? pred_t : too_t;
    const float* bias = sel ? biasP : biasO;
    unsigned short* out = sel ? outP : outO;
    const int Tlen = sel ? TR_ : TO_;
    const int toff = sel ? 0 : 4;
    const int mq = wv >> 1, tq = wv & 1;
    const int m0 = (yy & 1) * 128;
    const unsigned short* Xb = Xt + (size_t)b * T_ * 512;

    // staging descriptors (R=128: 1024 chunks, 4 instr/wave)
    int aSrc[4], bSrc[4], ldsO[4];
    #pragma unroll
    for (int i = 0; i < 4; ++i) {
      const int q = (wv << 8) + (i << 6) + l;
      const int r = q >> 3, c8s = (q & 7) ^ (r & 7);
      aSrc[i] = (m0 + r) * 512 + (c8s << 3);
      const int row = min(t0 + toff + r, T_ - 1);  // clamp: only t>=Tlen cols
      bSrc[i] = row * 512 + (c8s << 3);
      ldsO[i] = ((wv << 8) + (i << 6)) << 4;
    }

    f32x16 acc[2][2];
    #pragma unroll
    for (int i = 0; i < 2; ++i)
      #pragma unroll
      for (int jj = 0; jj < 2; ++jj)
        #pragma unroll
        for (int e = 0; e < 16; ++e) acc[i][jj][e] = 0.f;

    // prologue: stage chunk 0 into buffer 0
    #pragma unroll
    for (int i = 0; i < 4; ++i) gl16(Wbf + aSrc[i], Ab[0] + ldsO[i]);
    #pragma unroll
    for (int i = 0; i < 4; ++i) gl16(Xb + bSrc[i], Bb[0] + ldsO[i]);
    asm volatile("s_waitcnt vmcnt(0)" ::: "memory");
    __builtin_amdgcn_s_barrier();

    #pragma unroll
    for (int ps = 0; ps < 8; ++ps) {
      const int cb = ps & 1;
      if (ps < 7) {  // prefetch next chunk; target buf's readers all retired
        const int p0 = (ps + 1) << 6;
        #pragma unroll
        for (int i = 0; i < 4; ++i) gl16(Wbf + p0 + aSrc[i], Ab[cb ^ 1] + ldsO[i]);
        #pragma unroll
        for (int i = 0; i < 4; ++i) gl16(Xb + p0 + bSrc[i], Bb[cb ^ 1] + ldsO[i]);
      }
      const unsigned short* As = (const unsigned short*)Ab[cb];
      const unsigned short* Bs = (const unsigned short*)Bb[cb];
      #pragma unroll
      for (int s = 0; s < 4; ++s) {
        const int k8 = 2 * s + h;
        bf16x8 af[2], bfr[2];
        #pragma unroll
        for (int mt = 0; mt < 2; ++mt) {
          const int rm = 64 * mq + 32 * mt + tl;
          af[mt] = *(const bf16x8*)(As + rm * 64 + ((k8 ^ (rm & 7)) << 3));
        }
        #pragma unroll
        for (int nt = 0; nt < 2; ++nt) {
          const int rt = 64 * tq + 32 * nt + tl;
          bfr[nt] = *(const bf16x8*)(Bs + rt * 64 + ((k8 ^ (rt & 7)) << 3));
        }
        #pragma unroll
        for (int mt = 0; mt < 2; ++mt)
          #pragma unroll
          for (int nt = 0; nt < 2; ++nt)
            acc[mt][nt] = __builtin_amdgcn_mfma_f32_32x32x16_bf16(
                af[mt], bfr[nt], acc[mt][nt], 0, 0, 0);
      }
      asm volatile("s_waitcnt vmcnt(0)" ::: "memory");
      __builtin_amdgcn_s_barrier();
    }
    // epilogue: D layout col=lane&31 (t), row=(r&3)+8*(r>>2)+4*(lane>>5) (m)
    #pragma unroll
    for (int mt = 0; mt < 2; ++mt)
      #pragma unroll
      for (int nt = 0; nt < 2; ++nt)
        #pragma unroll
        for (int r = 0; r < 16; ++r) {
          const int hs = m0 + 64 * mq + 32 * mt + (r & 3) + 8 * (r >> 2) + 4 * h;
          const int t  = t0 + 64 * tq + 32 * nt + tl;
          if (t < Tlen)
            out[((size_t)b * HS_ + hs) * OPLD_ + t] = f2bf(acc[mt][nt][r] + bias[hs]);
        }
    return;
  }

  // ====================== inner path (v7, measured best) ======================
  char* const Pb[2] = { smem, smem + 16384 };           // predS dbuf (R=128)
  char* const Tb[2] = { smem + 32768, smem + 49152 };   // triS dbuf (2kf x 64)
  char* const TOOM  = smem + 65536;                     // too rows [0,96)
  char* const TAIL  = smem + 32768;                     // =Tb[0]: rows [96,160)
  const int mh = wv & 1, th = wv >> 1;
  const int kf0 = blockIdx.y * 2;
  const unsigned short* predB = pred_t + (size_t)b * T_ * NP_;
  const unsigned short* tooB  = too_t  + (size_t)b * T_ * NO_;
  const unsigned short* triK  = tri_bf + (size_t)kf0 * NO_ * NP_;

  // staging descriptors
  int pSrc[4], pLds[4];
  #pragma unroll
  for (int i = 0; i < 4; ++i) {
    const int q = (wv << 8) + (i << 6) + l;
    const int r = q >> 3, c8s = (q & 7) ^ (r & 7);
    pSrc[i] = (t0 + r) * NP_ + (c8s << 3);
    pLds[i] = ((wv << 8) + (i << 6)) << 4;
  }
  int tSrc[4], tLds[4];  // 2 kf x [64 m][64 p]: 1024 chunks, 4/wave
  #pragma unroll
  for (int i = 0; i < 4; ++i) {
    const int q = (wv << 8) + (i << 6) + l;
    const int f = q >> 9, qq = q & 511;
    const int r = qq >> 3, c8s = (qq & 7) ^ (r & 7);
    tSrc[i] = f * (NO_ * NP_) + r * NP_ + (c8s << 3);
    tLds[i] = ((wv << 8) + (i << 6)) << 4;
  }
  int oSrc[3], oLds[3];  // too rows [0,96): 768 chunks, 3/wave
  #pragma unroll
  for (int i = 0; i < 3; ++i) {
    const int q = wv * 192 + (i << 6) + l;
    const int r = q >> 3, c8s = (q & 7) ^ (r & 7);
    oSrc[i] = (t0 + r) * NO_ + (c8s << 3);  // t0+r <= 2015 < T_: no clamp
    oLds[i] = (wv * 192 + (i << 6)) << 4;
  }
  // tail rows [96,160): staged by waves 2,3 (4 gl16 each) at ps==7
  int aSrcT[4], aLdsT[4];
  {
    const int ws = (wv >= 2) ? (wv - 2) : 0;
    #pragma unroll
    for (int i = 0; i < 4; ++i) {
      const int q = (ws << 8) + (i << 6) + l;
      const int r = 96 + (q >> 3), c8s = (q & 7) ^ (r & 7);
      aSrcT[i] = min(t0 + r, T_ - 1) * NO_ + (c8s << 3);  // clamped rows feed
      aLdsT[i] = ((ws << 8) + (i << 6)) << 4;             // unused diagonals
    }
  }

  f32x16 Sacc[2][2];   // [kf][ct]
  #pragma unroll
  for (int f = 0; f < 2; ++f)
    #pragma unroll
    for (int ct = 0; ct < 2; ++ct)
      #pragma unroll
      for (int e = 0; e < 16; ++e) Sacc[f][ct][e] = 0.f;

  for (int mc = 0; mc < 8; ++mc) {
    const int m0 = mc << 6;
    const int mOff = m0 * NP_;
    // all waves finished Phase B reads (TOOM, TAIL, QS in Pb) of prev chunk
    __builtin_amdgcn_s_barrier();
    #pragma unroll
    for (int i = 0; i < 3; ++i) gl16(tooB + m0 + oSrc[i], TOOM + oLds[i]);
    #pragma unroll
    for (int i = 0; i < 4; ++i) gl16(triK + mOff + tSrc[i], Tb[0] + tLds[i]);
    #pragma unroll
    for (int i = 0; i < 4; ++i) gl16(predB + pSrc[i], Pb[0] + pLds[i]);
    asm volatile("s_waitcnt vmcnt(0)" ::: "memory");
    __builtin_amdgcn_s_barrier();

    f32x16 Qacc[2][2];  // [kf][nt]
    #pragma unroll
    for (int f = 0; f < 2; ++f)
      #pragma unroll
      for (int nt = 0; nt < 2; ++nt)
        #pragma unroll
        for (int e = 0; e < 16; ++e) Qacc[f][nt][e] = 0.f;

    #pragma unroll
    for (int ps = 0; ps < 8; ++ps) {
      const int cb = ps & 1;
      if (ps < 7) {  // prefetch next p-chunk; target buf's readers retired
        const int p1 = (ps + 1) << 6;
        #pragma unroll
        for (int i = 0; i < 4; ++i)
          gl16(triK + mOff + p1 + tSrc[i], Tb[cb ^ 1] + tLds[i]);
        #pragma unroll
        for (int i = 0; i < 4; ++i)
          gl16(predB + p1 + pSrc[i], Pb[cb ^ 1] + pLds[i]);
      }
      const unsigned short* predS = (const unsigned short*)Pb[cb];
      const unsigned short* triS  = (const unsigned short*)Tb[cb];
      #pragma unroll
      for (int s = 0; s < 4; ++s) {
        const int k8 = 2 * s + h;
        const int swz = (k8 ^ (tl & 7)) << 3;  // all row bases are 32-multiples
        bf16x8 a[2], bp[2];
        #pragma unroll
        for (int f = 0; f < 2; ++f)
          a[f] = *(const bf16x8*)(triS + f * 4096 + ((mh << 5) + tl) * 64 + swz);
        #pragma unroll
        for (int nt = 0; nt < 2; ++nt)
          bp[nt] = *(const bf16x8*)(predS + ((th << 6) + (nt << 5) + tl) * 64 + swz);
        #pragma unroll
        for (int f = 0; f < 2; ++f)
          #pragma unroll
          for (int nt = 0; nt < 2; ++nt)
            Qacc[f][nt] = __builtin_amdgcn_mfma_f32_32x32x16_bf16(
                a[f], bp[nt], Qacc[f][nt], 0, 0, 0);
      }
      if (ps == 7 && wv >= 2) {  // TOO tail rows [96,160) into dead Tb[0];
        #pragma unroll            // drained by this phase's vmcnt(0)+barrier
        for (int i = 0; i < 4; ++i)
          gl16(tooB + m0 + aSrcT[i], TAIL + aLdsT[i]);
      }
      asm volatile("s_waitcnt vmcnt(0)" ::: "memory");
      __builtin_amdgcn_s_barrier();
    }
    // ---- Phase B: Q -> bf16 -> QS in LDS (grouped layout). Wave (mh,th)
    // writes the mh-half (c8 = mh*4..+4) of slices (th*2+nt) of Pb[f].
    // Disjoint per wave; Pb bufs dead (all ps reads retired at ps7 barrier).
    #pragma unroll
    for (int f = 0; f < 2; ++f)
      #pragma unroll
      for (int nt = 0; nt < 2; ++nt) {
        unsigned short* QSw = (unsigned short*)(Pb[f] + (((th << 1) + nt) << 12));
        #pragma unroll
        for (int rp = 0; rp < 8; ++rp) {
          const int r = rp << 1;
          const int m = (mh << 5) + (r & 3) + ((r >> 2) << 3) + (h << 2);
          const int c8 = m >> 3, ml = m & 7;
          const int rX = (tl & 24) | ((tl ^ c8) & 7);
          const unsigned int pk = (unsigned int)f2bf(Qacc[f][nt][r]) |
                                  ((unsigned int)f2bf(Qacc[f][nt][r + 1]) << 16);
          *(unsigned int*)(QSw + (((c8 << 5) + rX) << 3) + ml) = pk;
        }
      }
    asm volatile("s_waitcnt lgkmcnt(0)" ::: "memory");
    __builtin_amdgcn_s_barrier();  // QS slices (2 writers each) visible
    #pragma unroll
    for (int s = 0; s < 4; ++s) {  // K=64 (m) in 4 steps of 16
      const int k8 = 2 * s + h;
      bf16x8 atoo[2];
      #pragma unroll
      for (int ct = 0; ct < 2; ++ct) {
        const int rbase = (wv + ct) << 5;          // too row t' = t0 + rbase + tl
        const int rr = rbase + tl;
        const unsigned short* tb = (rbase < 96)
            ? (const unsigned short*)TOOM + (size_t)rr * 64
            : (const unsigned short*)TAIL + (size_t)(rr - 96) * 64;
        atoo[ct] = *(const bf16x8*)(tb + ((k8 ^ (rr & 7)) << 3));
      }
      const int rqX = (tl & 24) | ((tl ^ k8) & 7);
      #pragma unroll
      for (int f = 0; f < 2; ++f) {
        const bf16x8 bq = *(const bf16x8*)((const unsigned short*)(Pb[f] + (wv << 12)) +
                                           (((k8 << 5) + rqX) << 3));
        #pragma unroll
        for (int ct = 0; ct < 2; ++ct)
          Sacc[f][ct] = __builtin_amdgcn_mfma_f32_32x32x16_bf16(atoo[ct], bq, Sacc[f][ct], 0, 0, 0);
      }
    }
  }
  // ---- extraction: S[c][t], c=(t-tc)+4+2j, tc = t0+32*wv
  __syncthreads();
  const int tglob = t0 + (wv << 5) + tl;
  float* SW = (float*)smem + (wv << 11);  // 8KB per wave
  #pragma unroll
  for (int f = 0; f < 2; ++f) {
    #pragma unroll
    for (int ct = 0; ct < 2; ++ct)
      #pragma unroll
      for (int r = 0; r < 16; ++r) {
        const int cc = (ct << 5) + (r & 3) + ((r >> 2) << 3) + (h << 2);
        SW[(cc << 5) + tl] = Sacc[f][ct][r];
      }
    if (tglob < TR_) {
      #pragma unroll
      for (int jj = 0; jj < 4; ++jj) {
        const int j = (jj << 1) + h;
        const float v = SW[((tl + 4 + 2 * j) << 5) + tl];
        inner[(((size_t)b * NF_ + j) * NF_ + (kf0 + f)) * TR_ + tglob] = v;
      }
    }
  }
}

// ---------------------------------------------------------------------------
// BN partial stats v2: vectorized loads. Thread tid handles t = tid*8..+8 via
// 1 pp uint4 + 3 op uint4. Per-element t+e<TR guard keeps pp garbage out.
// ---------------------------------------------------------------------------
__global__ __launch_bounds__(256) void bn_stats(
    const unsigned short* __restrict__ op, const unsigned short* __restrict__ pp,
    float* __restrict__ partials) {
  const int hh = blockIdx.x, b = blockIdx.y;
  const unsigned short* oprow = op + ((size_t)b * HS_ + hh) * OPLD_;
  const unsigned short* pprow = pp + ((size_t)b * HS_ + hh) * OPLD_;
  float s = 0.f, s2 = 0.f;
  const int t8 = threadIdx.x * 8;
  if (t8 < TR_) {
    uint4 pv4 = *(const uint4*)(pprow + t8);
    uint4 ov[3];
    ov[0] = *(const uint4*)(oprow + t8);
    ov[1] = *(const uint4*)(oprow + t8 + 8);
    ov[2] = *(const uint4*)(oprow + t8 + 16);
    float ppf[8], opf[24];
    #pragma unroll
    for (int i = 0; i < 4; ++i) {
      const unsigned int u = (&pv4.x)[i];
      ppf[2 * i]     = bf2f((unsigned short)(u & 0xffffu));
      ppf[2 * i + 1] = bf2f((unsigned short)(u >> 16));
    }
    #pragma unroll
    for (int g = 0; g < 3; ++g)
      #pragma unroll
      for (int i = 0; i < 4; ++i) {
        const unsigned int u = (&ov[g].x)[i];
        opf[8 * g + 2 * i]     = bf2f((unsigned short)(u & 0xffffu));
        opf[8 * g + 2 * i + 1] = bf2f((unsigned short)(u >> 16));
      }
    #pragma unroll
    for (int e = 0; e < 8; ++e) {
      if (t8 + e < TR_) {
        #pragma unroll
        for (int j = 0; j < NF_; ++j) {
          float r = fmaxf(opf[e + 2 * j] + ppf[e], 0.f);
          s += r; s2 += r * r;
        }
      }
    }
  }
  __shared__ float red[256], red2[256];
  red[threadIdx.x] = s; red2[threadIdx.x] = s2;
  __syncthreads();
  for (int st = 128; st > 0; st >>= 1) {
    if (threadIdx.x < st) {
      red[threadIdx.x]  += red[threadIdx.x + st];
      red2[threadIdx.x] += red2[threadIdx.x + st];
    }
    __syncthreads();
  }
  if (threadIdx.x == 0) {
    partials[b * HS_ + hh]            = red[0];
    partials[B_ * HS_ + b * HS_ + hh] = red2[0];
  }
}

__global__ __launch_bounds__(256) void bn_finalize(
    const float* __restrict__ partials, const float* __restrict__ gamma,
    const float* __restrict__ beta, const float* __restrict__ w_out,
    const float* __restrict__ b_out, float* __restrict__ w_eff,
    float* __restrict__ cvec) {
  const int hh = threadIdx.x;
  float s = 0.f, s2 = 0.f;
  for (int b = 0; b < B_; ++b) {
    s  += partials[b * HS_ + hh];
    s2 += partials[B_ * HS_ + b * HS_ + hh];
  }
  const float cnt  = (float)B_ * NF_ * TR_;
  const float mean = s / cnt;
  const float var  = s2 / cnt - mean * mean;
  const float scale = gamma[hh] * rsqrtf(var + EPS_);
  const float shift = beta[hh] - mean * scale;
  #pragma unroll
  for (int k = 0; k < NF_; ++k) w_eff[k * HS_ + hh] = w_out[k * HS_ + hh] * scale;
  __shared__ float red[256];
  for (int k = 0; k < NF_; ++k) {
    red[hh] = w_out[k * HS_ + hh] * shift;
    __syncthreads();
    for (int st = 128; st > 0; st >>= 1) {
      if (hh < st) red[hh] += red[hh + st];
      __syncthreads();
    }
    if (hh == 0) cvec[k] = b_out[k] + red[0];
    __syncthreads();
  }
}

// ---------------------------------------------------------------------------
// head + log-softmax diagonal v3: t-chunk 64, grid (32, B, 2) = 1024 blocks
// (4 blocks/CU, LDS ~20KB). One j per WAVE: tl = tid&63 -> t = t0+tl,
// jp = tid>>6 in [0,4), j = jh*4+jp. Staging shared by all 4 waves.
// opS cols [0,80) (needs tl+2j <= 63+14 = 77).
// ---------------------------------------------------------------------------
__global__ __launch_bounds__(256) void head_final(
    const unsigned short* __restrict__ op, const unsigned short* __restrict__ pp,
    const float* __restrict__ w_eff, const float* __restrict__ cvec,
    const float* __restrict__ inner, float* __restrict__ part3) {
  __shared__ float opS[80 * 20];  // [col][hh] col=t-t0 in [0,80)
  __shared__ float ppS[64 * 20];
  __shared__ float weS[8][256];
  __shared__ float red[4];
  const int tid = threadIdx.x;
  const int tl = tid & 63, jp = tid >> 6;
  const int t0 = blockIdx.x * 64;
  const int b  = blockIdx.y;
  const int jh = blockIdx.z;  // j half
  const int j  = (jh << 2) + jp;
  for (int i = tid; i < 8 * 256; i += 256) weS[i >> 8][i & 255] = w_eff[i];
  float acc[8] = {};
  const unsigned short* opb = op + (size_t)b * HS_ * OPLD_;
  const unsigned short* ppb = pp + (size_t)b * HS_ * OPLD_;
  for (int hc = 0; hc < 16; ++hc) {
    const int h0 = hc << 4;
    __syncthreads();
    if (tid < 160) {  // opS: 16 rows x 80 cols / 8
      const int r = tid / 10, cc = (tid - r * 10) << 3;
      const int g = min(t0 + cc, OPLD_ - 8);
      uint4 v = *(const uint4*)(opb + (size_t)(h0 + r) * OPLD_ + g);
      #pragma unroll
      for (int e = 0; e < 4; ++e) {
        const unsigned int u = (&v.x)[e];
        opS[(cc + 2 * e) * 20 + r]     = bf2f((unsigned short)(u & 0xffffu));
        opS[(cc + 2 * e + 1) * 20 + r] = bf2f((unsigned short)(u >> 16));
      }
    }
    if (tid < 128) {  // ppS: 16 rows x 64 cols / 8
      const int r = tid >> 3, cc = (tid & 7) << 3;
      uint4 v = *(const uint4*)(ppb + (size_t)(h0 + r) * OPLD_ + t0 + cc);
      #pragma unroll
      for (int e = 0; e < 4; ++e) {
        const unsigned int u = (&v.x)[e];
        ppS[(cc + 2 * e) * 20 + r]     = bf2f((unsigned short)(u & 0xffffu));
        ppS[(cc + 2 * e + 1) * 20 + r] = bf2f((unsigned short)(u >> 16));
      }
    }
    __syncthreads();
    float pv[16];
    #pragma unroll
    for (int i = 0; i < 4; ++i) {
      float4 q = *(const float4*)(ppS + tl * 20 + 4 * i);
      pv[4 * i + 0] = q.x; pv[4 * i + 1] = q.y;
      pv[4 * i + 2] = q.z; pv[4 * i + 3] = q.w;
    }
    const int col = tl + 2 * j;
    #pragma unroll
    for (int i = 0; i < 4; ++i) {
      float4 ov = *(const float4*)(opS + col * 20 + 4 * i);
      #pragma unroll
      for (int e = 0; e < 4; ++e) {
        const float r = fmaxf((&ov.x)[e] + pv[4 * i + e], 0.f);
        #pragma unroll
        for (int k = 0; k < 8; ++k) acc[k] += weS[k][h0 + 4 * i + e] * r;
      }
    }
  }
  const int t = t0 + tl;
  float sj = 0.f;
  if (t < TR_) {
    float v[8]; float mx = -1e30f;
    #pragma unroll
    for (int k = 0; k < 8; ++k) {
      v[k] = acc[k] + cvec[k] +
             inner[(((size_t)b * NF_ + j) * NF_ + k) * TR_ + t];
      mx = fmaxf(mx, v[k]);
    }
    float se = 0.f;
    #pragma unroll
    for (int k = 0; k < 8; ++k) se += expf(v[k] - mx);
    sj = v[j] - mx - logf(se);
  }
  #pragma unroll
  for (int off = 32; off > 0; off >>= 1) sj += __shfl_down(sj, off);
  if ((tid & 63) == 0) red[jp] = sj;
  __syncthreads();
  if (tid < 4) {
    const int jw = (jh << 2) + tid;
    part3[(jw * B_ + b) * 32 + blockIdx.x] = red[tid];
  }
}

__global__ void final_out(const float* __restrict__ part3, float* __restrict__ out) {
  const int j = threadIdx.x;
  if (j < NF_) {
    float s = 0.f;
    for (int i = 0; i < B_ * 32; ++i) s += part3[j * B_ * 32 + i];
    out[j] = s / ((float)B_ * (float)TR_);
  }
}

// ---------------------------------------------------------------------------
extern "C" void kernel_launch(void* const* d_in, const int* in_sizes, int n_in,
                              void* d_out, int out_size, void* d_ws, size_t ws_size,
                              hipStream_t stream) {
  const float* predictor = (const float*)d_in[0];
  const float* to_order  = (const float*)d_in[1];
  const float* trilinear = (const float*)d_in[2];
  const float* w_o   = (const float*)d_in[3];
  const float* b_o   = (const float*)d_in[4];
  const float* w_p   = (const float*)d_in[5];
  const float* b_p   = (const float*)d_in[6];
  const float* bn_g  = (const float*)d_in[7];
  const float* bn_b  = (const float*)d_in[8];
  const float* w_out = (const float*)d_in[9];
  const float* b_out = (const float*)d_in[10];
  float* out = (float*)d_out;

  char* w = (char*)d_ws;
  unsigned short* pred_t = (unsigned short*)w; w += (size_t)B_ * T_ * NP_ * 2;
  unsigned short* too_t  = (unsigned short*)w; w += (size_t)B_ * T_ * NO_ * 2;
  unsigned short* tri_bf = (unsigned short*)w; w += (size_t)NF_ * NO_ * NP_ * 2;
  unsigned short* wo_bf  = (unsigned short*)w; w += (size_t)HS_ * NO_ * 2;
  unsigned short* wp_bf  = (unsigned short*)w; w += (size_t)HS_ * NP_ * 2;
  unsigned short* o_proj = (unsigned short*)w; w += (size_t)B_ * HS_ * OPLD_ * 2;
  unsigned short* p_proj = (unsigned short*)w; w += (size_t)B_ * HS_ * OPLD_ * 2;
  float* inner    = (float*)w; w += (size_t)B_ * NF_ * NF_ * TR_ * 4;
  float* partials = (float*)w; w += (size_t)2 * B_ * HS_ * 4;
  float* w_eff    = (float*)w; w += (size_t)NF_ * HS_ * 4;
  float* cvec     = (float*)w; w += 256;
  float* part3    = (float*)w; w += (size_t)NF_ * B_ * 32 * 4;

  transpose_cvt<<<dim3(32, 8, 32), 256, 0, stream>>>(predictor, pred_t,
                                                     to_order, too_t);
  cvt_all<<<2304, 256, 0, stream>>>(trilinear, tri_bf, w_o, wo_bf, w_p, wp_bf);

  proj_inner_mfma<<<dim3(16, 8, 16), 256, 0, stream>>>(
      pred_t, too_t, tri_bf, inner,
      wo_bf, wp_bf, b_o, b_p, o_proj, p_proj);

  bn_stats<<<dim3(HS_, B_), 256, 0, stream>>>(o_proj, p_proj, partials);
  bn_finalize<<<1, 256, 0, stream>>>(partials, bn_g, bn_b, w_out, b_out, w_eff, cvec);
  head_final<<<dim3(32, B_, 2), 256, 0, stream>>>(o_proj, p_proj, w_eff, cvec, inner, part3);
  final_out<<<1, 64, 0, stream>>>(part3, out);
}

// Round 11
// 329.631 us; speedup vs baseline: 1.0354x; 1.0354x over previous
//
#include <hip/hip_runtime.h>
#include <math.h>

// Problem constants (fixed by reference)
constexpr int B_  = 16;
constexpr int NP_ = 512;
constexpr int NO_ = 512;
constexpr int T_  = 2048;
constexpr int NF_ = 8;
constexpr int HS_ = 256;
constexpr int TR_ = 2030;   // T - (DELAY + SKIP*(NF-1))
constexpr int TO_ = 2044;   // T - DELAY
constexpr int OPLD_ = 2048; // padded row stride for proj outputs
constexpr float EPS_ = 1e-5f;

typedef short bf16x8 __attribute__((ext_vector_type(8)));
typedef float f32x16 __attribute__((ext_vector_type(16)));

__device__ __forceinline__ unsigned short f2bf(float f) {
  union { float f; unsigned int u; } v; v.f = f;
  unsigned int r = v.u + 0x7fffu + ((v.u >> 16) & 1u);  // RNE
  return (unsigned short)(r >> 16);
}
__device__ __forceinline__ float bf2f(unsigned short u) {
  union { unsigned int u; float f; } v; v.u = ((unsigned int)u) << 16;
  return v.f;
}

// global -> LDS direct (16B/lane). LDS dest = wave-uniform base + lane*16.
typedef const __attribute__((address_space(1))) unsigned int* gas_u32;
typedef __attribute__((address_space(3))) unsigned int* las_u32;
__device__ __forceinline__ void gl16(const void* g, void* l) {
  __builtin_amdgcn_global_load_lds((gas_u32)g, (las_u32)l, 16, 0, 0);
}

// Tile geometry: [R][64] bf16 tiles, 128B rows. LDS chunk index for (row r,
// col-chunk c8) is r*8 + (c8 ^ (r&7)).  Staging: lane handling linear chunk q
// covers row r=q>>3, source col-chunk (q&7)^(r&7) -> coalesced 128B/8-lanes.
// Fragment read (row rr, k-chunk k8): elem offset rr*64 + ((k8^(rr&7))<<3).

// ---------------------------------------------------------------------------
// Transpose + cast (merged): z<16 -> predictor->pred_t (b=z); z>=16 ->
// to_order->too_t (b=z-16). in f32 [b][512][2048] -> out bf16 [b][2048][512]
// ---------------------------------------------------------------------------
__global__ __launch_bounds__(256) void transpose_cvt(
    const float* __restrict__ inA, unsigned short* __restrict__ outA,
    const float* __restrict__ inB, unsigned short* __restrict__ outB) {
  __shared__ float tile[64][65];
  const int c0 = blockIdx.x * 64;  // t dim
  const int r0 = blockIdx.y * 64;  // p dim
  const int z  = blockIdx.z;
  const int b  = z & 15;
  const float* ib = ((z < 16) ? inA : inB) + (size_t)b * 512 * 2048;
  unsigned short* ob = ((z < 16) ? outA : outB) + (size_t)b * 2048 * 512;
  for (int i = threadIdx.x; i < 64 * 16; i += 256) {
    const int r = i >> 4, c4 = (i & 15) * 4;
    float4 v = *(const float4*)(ib + (size_t)(r0 + r) * 2048 + c0 + c4);
    tile[r][c4 + 0] = v.x; tile[r][c4 + 1] = v.y;
    tile[r][c4 + 2] = v.z; tile[r][c4 + 3] = v.w;
  }
  __syncthreads();
  for (int i = threadIdx.x; i < 64 * 8; i += 256) {
    const int c = i >> 3, r8 = (i & 7) * 8;
    unsigned int pk[4];
    #pragma unroll
    for (int e = 0; e < 4; ++e)
      pk[e] = (unsigned int)f2bf(tile[r8 + 2 * e][c]) |
              ((unsigned int)f2bf(tile[r8 + 2 * e + 1][c]) << 16);
    *(uint4*)(ob + (size_t)(c0 + c) * 512 + r0 + r8) = *(uint4*)pk;
  }
}

// Elementwise f32 -> bf16, three tensors range-dispatched in one launch.
__global__ __launch_bounds__(256) void cvt_all(
    const float* __restrict__ tri, unsigned short* __restrict__ trib,
    const float* __restrict__ wo, unsigned short* __restrict__ wob,
    const float* __restrict__ wp, unsigned short* __restrict__ wpb) {
  const int n1 = NF_ * NO_ * NP_, n2 = HS_ * 512;
  int i = (blockIdx.x * 256 + threadIdx.x) * 4;
  const float* in; unsigned short* out;
  if (i < n1)           { in = tri; out = trib; }
  else if (i < n1 + n2) { i -= n1; in = wo; out = wob; }
  else                  { i -= n1 + n2; in = wp; out = wpb; }
  float4 v = *(const float4*)(in + i);
  ushort4 o; o.x = f2bf(v.x); o.y = f2bf(v.y); o.z = f2bf(v.z); o.w = f2bf(v.w);
  *(ushort4*)(out + i) = o;
}

// ---------------------------------------------------------------------------
// proj MFMA (merged o/p): out[b,hs,t] = sum_d W[hs,d]*Xt[b,t+toff,d] + bias
// grid.y in [0,4): sel = y>>1 (0: o-proj from too_t, 1: p-proj from pred_t),
// m0 = (y&1)*128. 128m x 128t tile, K=512 in 8 chunks of 64. 2-phase
// pipeline: [issue next into other buf] -> compute -> vmcnt(0) -> barrier.
// ---------------------------------------------------------------------------
__global__ __launch_bounds__(256, 2) void proj_mfma(
    const unsigned short* __restrict__ Wo, const unsigned short* __restrict__ Wp,
    const unsigned short* __restrict__ Xo, const unsigned short* __restrict__ Xp,
    const float* __restrict__ biasO, const float* __restrict__ biasP,
    unsigned short* __restrict__ outO, unsigned short* __restrict__ outP) {
  __shared__ char smem[65536];
  char* const Ab[2] = { smem, smem + 16384 };
  char* const Bb[2] = { smem + 32768, smem + 49152 };
  const int sel = blockIdx.y >> 1;
  const unsigned short* Wbf = sel ? Wp : Wo;
  const unsigned short* Xt  = sel ? Xp : Xo;
  const float* bias = sel ? biasP : biasO;
  unsigned short* out = sel ? outP : outO;
  const int Tlen = sel ? TR_ : TO_;
  const int toff = sel ? 0 : 4;
  const int tid = threadIdx.x;
  const int l = tid & 63, wv = tid >> 6;
  const int h = l >> 5, tl = l & 31;
  const int mq = wv >> 1, tq = wv & 1;
  const int t0 = blockIdx.x * 128;
  const int m0 = (blockIdx.y & 1) * 128;
  const int b  = blockIdx.z;
  const unsigned short* Xb = Xt + (size_t)b * T_ * 512;

  // staging descriptors (R=128: 1024 chunks, 4 instr/wave)
  int aSrc[4], bSrc[4], ldsO[4];
  #pragma unroll
  for (int i = 0; i < 4; ++i) {
    const int q = (wv << 8) + (i << 6) + l;
    const int r = q >> 3, c8s = (q & 7) ^ (r & 7);
    aSrc[i] = (m0 + r) * 512 + (c8s << 3);
    const int row = min(t0 + toff + r, T_ - 1);  // clamp: only t>=Tlen cols
    bSrc[i] = row * 512 + (c8s << 3);
    ldsO[i] = ((wv << 8) + (i << 6)) << 4;
  }

  f32x16 acc[2][2];
  #pragma unroll
  for (int i = 0; i < 2; ++i)
    #pragma unroll
    for (int jj = 0; jj < 2; ++jj)
      #pragma unroll
      for (int e = 0; e < 16; ++e) acc[i][jj][e] = 0.f;

  // prologue: stage chunk 0 into buffer 0
  #pragma unroll
  for (int i = 0; i < 4; ++i) gl16(Wbf + aSrc[i], Ab[0] + ldsO[i]);
  #pragma unroll
  for (int i = 0; i < 4; ++i) gl16(Xb + bSrc[i], Bb[0] + ldsO[i]);
  asm volatile("s_waitcnt vmcnt(0)" ::: "memory");
  __builtin_amdgcn_s_barrier();

  #pragma unroll
  for (int ps = 0; ps < 8; ++ps) {
    const int cb = ps & 1;
    if (ps < 7) {  // prefetch next chunk; target buf's readers all retired
      const int p0 = (ps + 1) << 6;
      #pragma unroll
      for (int i = 0; i < 4; ++i) gl16(Wbf + p0 + aSrc[i], Ab[cb ^ 1] + ldsO[i]);
      #pragma unroll
      for (int i = 0; i < 4; ++i) gl16(Xb + p0 + bSrc[i], Bb[cb ^ 1] + ldsO[i]);
    }
    const unsigned short* As = (const unsigned short*)Ab[cb];
    const unsigned short* Bs = (const unsigned short*)Bb[cb];
    #pragma unroll
    for (int s = 0; s < 4; ++s) {
      const int k8 = 2 * s + h;
      bf16x8 af[2], bfr[2];
      #pragma unroll
      for (int mt = 0; mt < 2; ++mt) {
        const int rm = 64 * mq + 32 * mt + tl;
        af[mt] = *(const bf16x8*)(As + rm * 64 + ((k8 ^ (rm & 7)) << 3));
      }
      #pragma unroll
      for (int nt = 0; nt < 2; ++nt) {
        const int rt = 64 * tq + 32 * nt + tl;
        bfr[nt] = *(const bf16x8*)(Bs + rt * 64 + ((k8 ^ (rt & 7)) << 3));
      }
      #pragma unroll
      for (int mt = 0; mt < 2; ++mt)
        #pragma unroll
        for (int nt = 0; nt < 2; ++nt)
          acc[mt][nt] = __builtin_amdgcn_mfma_f32_32x32x16_bf16(
              af[mt], bfr[nt], acc[mt][nt], 0, 0, 0);
    }
    asm volatile("s_waitcnt vmcnt(0)" ::: "memory");
    __builtin_amdgcn_s_barrier();
  }
  // epilogue: D layout col=lane&31 (t), row=(r&3)+8*(r>>2)+4*(lane>>5) (m)
  #pragma unroll
  for (int mt = 0; mt < 2; ++mt)
    #pragma unroll
    for (int nt = 0; nt < 2; ++nt)
      #pragma unroll
      for (int r = 0; r < 16; ++r) {
        const int hs = m0 + 64 * mq + 32 * mt + (r & 3) + 8 * (r >> 2) + 4 * h;
        const int t  = t0 + 64 * tq + 32 * nt + tl;
        if (t < Tlen)
          out[((size_t)b * HS_ + hs) * OPLD_ + t] = f2bf(acc[mt][nt][r] + bias[hs]);
      }
}

// ---------------------------------------------------------------------------
// inner MFMA v7 (measured best): m-split Phase A, 4 reads/4 MFMAs.
// Wave (mh=wv&1, th=wv>>1) computes Qacc[f][nt] for m rows mh*32..+32,
// t cols th*64+nt*32..+32. Phase B: QS slice (th*2+nt) of Pb[f] co-written by
// mh halves -> lgkmcnt(0)+barrier between QS write and read. Banded MFMA +
// extraction as v6. LDS 76KB: Pb 2x16K | Tb 2x16K (Tb[0] = TOO tail) |
// TOOM 12K. 2 blocks/CU (152KB), 8 waves/CU.
// ---------------------------------------------------------------------------
__global__ __launch_bounds__(256, 2) void inner_mfma(
    const unsigned short* __restrict__ pred_t,  // [B][T][NP] bf16
    const unsigned short* __restrict__ too_t,   // [B][T][NO] bf16
    const unsigned short* __restrict__ tri_bf,  // [NF][NO][NP] bf16
    float* __restrict__ inner) {                // [B][NF][NF][TR] f32
  __shared__ char smem[77824];
  char* const Pb[2] = { smem, smem + 16384 };           // predS dbuf (R=128)
  char* const Tb[2] = { smem + 32768, smem + 49152 };   // triS dbuf (2kf x 64)
  char* const TOOM  = smem + 65536;                     // too rows [0,96)
  char* const TAIL  = smem + 32768;                     // =Tb[0]: rows [96,160)
  const int tid = threadIdx.x;
  const int l = tid & 63, wv = tid >> 6;
  const int h = l >> 5, tl = l & 31;
  const int mh = wv & 1, th = wv >> 1;
  const int t0 = blockIdx.x * 128;
  const int kf0 = blockIdx.y * 2;
  const int b  = blockIdx.z;
  const unsigned short* predB = pred_t + (size_t)b * T_ * NP_;
  const unsigned short* tooB  = too_t  + (size_t)b * T_ * NO_;
  const unsigned short* triK  = tri_bf + (size_t)kf0 * NO_ * NP_;

  // staging descriptors
  int pSrc[4], pLds[4];
  #pragma unroll
  for (int i = 0; i < 4; ++i) {
    const int q = (wv << 8) + (i << 6) + l;
    const int r = q >> 3, c8s = (q & 7) ^ (r & 7);
    pSrc[i] = (t0 + r) * NP_ + (c8s << 3);
    pLds[i] = ((wv << 8) + (i << 6)) << 4;
  }
  int tSrc[4], tLds[4];  // 2 kf x [64 m][64 p]: 1024 chunks, 4/wave
  #pragma unroll
  for (int i = 0; i < 4; ++i) {
    const int q = (wv << 8) + (i << 6) + l;
    const int f = q >> 9, qq = q & 511;
    const int r = qq >> 3, c8s = (qq & 7) ^ (r & 7);
    tSrc[i] = f * (NO_ * NP_) + r * NP_ + (c8s << 3);
    tLds[i] = ((wv << 8) + (i << 6)) << 4;
  }
  int oSrc[3], oLds[3];  // too rows [0,96): 768 chunks, 3/wave
  #pragma unroll
  for (int i = 0; i < 3; ++i) {
    const int q = wv * 192 + (i << 6) + l;
    const int r = q >> 3, c8s = (q & 7) ^ (r & 7);
    oSrc[i] = (t0 + r) * NO_ + (c8s << 3);  // t0+r <= 2015 < T_: no clamp
    oLds[i] = (wv * 192 + (i << 6)) << 4;
  }
  // tail rows [96,160): staged by waves 2,3 (4 gl16 each) at ps==7
  int aSrcT[4], aLdsT[4];
  {
    const int ws = (wv >= 2) ? (wv - 2) : 0;
    #pragma unroll
    for (int i = 0; i < 4; ++i) {
      const int q = (ws << 8) + (i << 6) + l;
      const int r = 96 + (q >> 3), c8s = (q & 7) ^ (r & 7);
      aSrcT[i] = min(t0 + r, T_ - 1) * NO_ + (c8s << 3);  // clamped rows feed
      aLdsT[i] = ((ws << 8) + (i << 6)) << 4;             // unused diagonals
    }
  }

  f32x16 Sacc[2][2];   // [kf][ct]
  #pragma unroll
  for (int f = 0; f < 2; ++f)
    #pragma unroll
    for (int ct = 0; ct < 2; ++ct)
      #pragma unroll
      for (int e = 0; e < 16; ++e) Sacc[f][ct][e] = 0.f;

  for (int mc = 0; mc < 8; ++mc) {
    const int m0 = mc << 6;
    const int mOff = m0 * NP_;
    // all waves finished Phase B reads (TOOM, TAIL, QS in Pb) of prev chunk
    __builtin_amdgcn_s_barrier();
    #pragma unroll
    for (int i = 0; i < 3; ++i) gl16(tooB + m0 + oSrc[i], TOOM + oLds[i]);
    #pragma unroll
    for (int i = 0; i < 4; ++i) gl16(triK + mOff + tSrc[i], Tb[0] + tLds[i]);
    #pragma unroll
    for (int i = 0; i < 4; ++i) gl16(predB + pSrc[i], Pb[0] + pLds[i]);
    asm volatile("s_waitcnt vmcnt(0)" ::: "memory");
    __builtin_amdgcn_s_barrier();

    f32x16 Qacc[2][2];  // [kf][nt]
    #pragma unroll
    for (int f = 0; f < 2; ++f)
      #pragma unroll
      for (int nt = 0; nt < 2; ++nt)
        #pragma unroll
        for (int e = 0; e < 16; ++e) Qacc[f][nt][e] = 0.f;

    #pragma unroll
    for (int ps = 0; ps < 8; ++ps) {
      const int cb = ps & 1;
      if (ps < 7) {  // prefetch next p-chunk; target buf's readers retired
        const int p1 = (ps + 1) << 6;
        #pragma unroll
        for (int i = 0; i < 4; ++i)
          gl16(triK + mOff + p1 + tSrc[i], Tb[cb ^ 1] + tLds[i]);
        #pragma unroll
        for (int i = 0; i < 4; ++i)
          gl16(predB + p1 + pSrc[i], Pb[cb ^ 1] + pLds[i]);
      }
      const unsigned short* predS = (const unsigned short*)Pb[cb];
      const unsigned short* triS  = (const unsigned short*)Tb[cb];
      #pragma unroll
      for (int s = 0; s < 4; ++s) {
        const int k8 = 2 * s + h;
        const int swz = (k8 ^ (tl & 7)) << 3;  // all row bases are 32-multiples
        bf16x8 a[2], bp[2];
        #pragma unroll
        for (int f = 0; f < 2; ++f)
          a[f] = *(const bf16x8*)(triS + f * 4096 + ((mh << 5) + tl) * 64 + swz);
        #pragma unroll
        for (int nt = 0; nt < 2; ++nt)
          bp[nt] = *(const bf16x8*)(predS + ((th << 6) + (nt << 5) + tl) * 64 + swz);
        #pragma unroll
        for (int f = 0; f < 2; ++f)
          #pragma unroll
          for (int nt = 0; nt < 2; ++nt)
            Qacc[f][nt] = __builtin_amdgcn_mfma_f32_32x32x16_bf16(
                a[f], bp[nt], Qacc[f][nt], 0, 0, 0);
      }
      if (ps == 7 && wv >= 2) {  // TOO tail rows [96,160) into dead Tb[0];
        #pragma unroll            // drained by this phase's vmcnt(0)+barrier
        for (int i = 0; i < 4; ++i)
          gl16(tooB + m0 + aSrcT[i], TAIL + aLdsT[i]);
      }
      asm volatile("s_waitcnt vmcnt(0)" ::: "memory");
      __builtin_amdgcn_s_barrier();
    }
    // ---- Phase B: Q -> bf16 -> QS in LDS (grouped layout). Wave (mh,th)
    // writes the mh-half (c8 = mh*4..+4) of slices (th*2+nt) of Pb[f].
    // Disjoint per wave; Pb bufs dead (all ps reads retired at ps7 barrier).
    #pragma unroll
    for (int f = 0; f < 2; ++f)
      #pragma unroll
      for (int nt = 0; nt < 2; ++nt) {
        unsigned short* QSw = (unsigned short*)(Pb[f] + (((th << 1) + nt) << 12));
        #pragma unroll
        for (int rp = 0; rp < 8; ++rp) {
          const int r = rp << 1;
          const int m = (mh << 5) + (r & 3) + ((r >> 2) << 3) + (h << 2);
          const int c8 = m >> 3, ml = m & 7;
          const int rX = (tl & 24) | ((tl ^ c8) & 7);
          const unsigned int pk = (unsigned int)f2bf(Qacc[f][nt][r]) |
                                  ((unsigned int)f2bf(Qacc[f][nt][r + 1]) << 16);
          *(unsigned int*)(QSw + (((c8 << 5) + rX) << 3) + ml) = pk;
        }
      }
    asm volatile("s_waitcnt lgkmcnt(0)" ::: "memory");
    __builtin_amdgcn_s_barrier();  // QS slices (2 writers each) visible
    #pragma unroll
    for (int s = 0; s < 4; ++s) {  // K=64 (m) in 4 steps of 16
      const int k8 = 2 * s + h;
      bf16x8 atoo[2];
      #pragma unroll
      for (int ct = 0; ct < 2; ++ct) {
        const int rbase = (wv + ct) << 5;          // too row t' = t0 + rbase + tl
        const int rr = rbase + tl;
        const unsigned short* tb = (rbase < 96)
            ? (const unsigned short*)TOOM + (size_t)rr * 64
            : (const unsigned short*)TAIL + (size_t)(rr - 96) * 64;
        atoo[ct] = *(const bf16x8*)(tb + ((k8 ^ (rr & 7)) << 3));
      }
      const int rqX = (tl & 24) | ((tl ^ k8) & 7);
      #pragma unroll
      for (int f = 0; f < 2; ++f) {
        const bf16x8 bq = *(const bf16x8*)((const unsigned short*)(Pb[f] + (wv << 12)) +
                                           (((k8 << 5) + rqX) << 3));
        #pragma unroll
        for (int ct = 0; ct < 2; ++ct)
          Sacc[f][ct] = __builtin_amdgcn_mfma_f32_32x32x16_bf16(atoo[ct], bq, Sacc[f][ct], 0, 0, 0);
      }
    }
  }
  // ---- extraction: S[c][t], c=(t-tc)+4+2j, tc = t0+32*wv
  __syncthreads();
  const int tglob = t0 + (wv << 5) + tl;
  float* SW = (float*)smem + (wv << 11);  // 8KB per wave
  #pragma unroll
  for (int f = 0; f < 2; ++f) {
    #pragma unroll
    for (int ct = 0; ct < 2; ++ct)
      #pragma unroll
      for (int r = 0; r < 16; ++r) {
        const int cc = (ct << 5) + (r & 3) + ((r >> 2) << 3) + (h << 2);
        SW[(cc << 5) + tl] = Sacc[f][ct][r];
      }
    if (tglob < TR_) {
      #pragma unroll
      for (int jj = 0; jj < 4; ++jj) {
        const int j = (jj << 1) + h;
        const float v = SW[((tl + 4 + 2 * j) << 5) + tl];
        inner[(((size_t)b * NF_ + j) * NF_ + (kf0 + f)) * TR_ + tglob] = v;
      }
    }
  }
}

// ---------------------------------------------------------------------------
// BN partial stats v2: vectorized loads. Thread tid handles t = tid*8..+8 via
// 1 pp uint4 + 3 op uint4. Per-element t+e<TR guard keeps pp garbage out.
// ---------------------------------------------------------------------------
__global__ __launch_bounds__(256) void bn_stats(
    const unsigned short* __restrict__ op, const unsigned short* __restrict__ pp,
    float* __restrict__ partials) {
  const int hh = blockIdx.x, b = blockIdx.y;
  const unsigned short* oprow = op + ((size_t)b * HS_ + hh) * OPLD_;
  const unsigned short* pprow = pp + ((size_t)b * HS_ + hh) * OPLD_;
  float s = 0.f, s2 = 0.f;
  const int t8 = threadIdx.x * 8;
  if (t8 < TR_) {
    uint4 pv4 = *(const uint4*)(pprow + t8);
    uint4 ov[3];
    ov[0] = *(const uint4*)(oprow + t8);
    ov[1] = *(const uint4*)(oprow + t8 + 8);
    ov[2] = *(const uint4*)(oprow + t8 + 16);
    float ppf[8], opf[24];
    #pragma unroll
    for (int i = 0; i < 4; ++i) {
      const unsigned int u = (&pv4.x)[i];
      ppf[2 * i]     = bf2f((unsigned short)(u & 0xffffu));
      ppf[2 * i + 1] = bf2f((unsigned short)(u >> 16));
    }
    #pragma unroll
    for (int g = 0; g < 3; ++g)
      #pragma unroll
      for (int i = 0; i < 4; ++i) {
        const unsigned int u = (&ov[g].x)[i];
        opf[8 * g + 2 * i]     = bf2f((unsigned short)(u & 0xffffu));
        opf[8 * g + 2 * i + 1] = bf2f((unsigned short)(u >> 16));
      }
    #pragma unroll
    for (int e = 0; e < 8; ++e) {
      if (t8 + e < TR_) {
        #pragma unroll
        for (int j = 0; j < NF_; ++j) {
          float r = fmaxf(opf[e + 2 * j] + ppf[e], 0.f);
          s += r; s2 += r * r;
        }
      }
    }
  }
  __shared__ float red[256], red2[256];
  red[threadIdx.x] = s; red2[threadIdx.x] = s2;
  __syncthreads();
  for (int st = 128; st > 0; st >>= 1) {
    if (threadIdx.x < st) {
      red[threadIdx.x]  += red[threadIdx.x + st];
      red2[threadIdx.x] += red2[threadIdx.x + st];
    }
    __syncthreads();
  }
  if (threadIdx.x == 0) {
    partials[b * HS_ + hh]            = red[0];
    partials[B_ * HS_ + b * HS_ + hh] = red2[0];
  }
}

__global__ __launch_bounds__(256) void bn_finalize(
    const float* __restrict__ partials, const float* __restrict__ gamma,
    const float* __restrict__ beta, const float* __restrict__ w_out,
    const float* __restrict__ b_out, float* __restrict__ w_eff,
    float* __restrict__ cvec) {
  const int hh = threadIdx.x;
  float s = 0.f, s2 = 0.f;
  for (int b = 0; b < B_; ++b) {
    s  += partials[b * HS_ + hh];
    s2 += partials[B_ * HS_ + b * HS_ + hh];
  }
  const float cnt  = (float)B_ * NF_ * TR_;
  const float mean = s / cnt;
  const float var  = s2 / cnt - mean * mean;
  const float scale = gamma[hh] * rsqrtf(var + EPS_);
  const float shift = beta[hh] - mean * scale;
  #pragma unroll
  for (int k = 0; k < NF_; ++k) w_eff[k * HS_ + hh] = w_out[k * HS_ + hh] * scale;
  __shared__ float red[256];
  for (int k = 0; k < NF_; ++k) {
    red[hh] = w_out[k * HS_ + hh] * shift;
    __syncthreads();
    for (int st = 128; st > 0; st >>= 1) {
      if (hh < st) red[hh] += red[hh + st];
      __syncthreads();
    }
    if (hh == 0) cvec[k] = b_out[k] + red[0];
    __syncthreads();
  }
}

// ---------------------------------------------------------------------------
// head + log-softmax diagonal v3: t-chunk 64, grid (32, B, 2) = 1024 blocks
// (4 blocks/CU, LDS ~20KB). One j per WAVE: tl = tid&63 -> t = t0+tl,
// jp = tid>>6 in [0,4), j = jh*4+jp. Staging shared by all 4 waves.
// opS cols [0,80) (needs tl+2j <= 63+14 = 77).
// ---------------------------------------------------------------------------
__global__ __launch_bounds__(256) void head_final(
    const unsigned short* __restrict__ op, const unsigned short* __restrict__ pp,
    const float* __restrict__ w_eff, const float* __restrict__ cvec,
    const float* __restrict__ inner, float* __restrict__ part3) {
  __shared__ float opS[80 * 20];  // [col][hh] col=t-t0 in [0,80)
  __shared__ float ppS[64 * 20];
  __shared__ float weS[8][256];
  __shared__ float red[4];
  const int tid = threadIdx.x;
  const int tl = tid & 63, jp = tid >> 6;
  const int t0 = blockIdx.x * 64;
  const int b  = blockIdx.y;
  const int jh = blockIdx.z;  // j half
  const int j  = (jh << 2) + jp;
  for (int i = tid; i < 8 * 256; i += 256) weS[i >> 8][i & 255] = w_eff[i];
  float acc[8] = {};
  const unsigned short* opb = op + (size_t)b * HS_ * OPLD_;
  const unsigned short* ppb = pp + (size_t)b * HS_ * OPLD_;
  for (int hc = 0; hc < 16; ++hc) {
    const int h0 = hc << 4;
    __syncthreads();
    if (tid < 160) {  // opS: 16 rows x 80 cols / 8
      const int r = tid / 10, cc = (tid - r * 10) << 3;
      const int g = min(t0 + cc, OPLD_ - 8);
      uint4 v = *(const uint4*)(opb + (size_t)(h0 + r) * OPLD_ + g);
      #pragma unroll
      for (int e = 0; e < 4; ++e) {
        const unsigned int u = (&v.x)[e];
        opS[(cc + 2 * e) * 20 + r]     = bf2f((unsigned short)(u & 0xffffu));
        opS[(cc + 2 * e + 1) * 20 + r] = bf2f((unsigned short)(u >> 16));
      }
    }
    if (tid < 128) {  // ppS: 16 rows x 64 cols / 8
      const int r = tid >> 3, cc = (tid & 7) << 3;
      uint4 v = *(const uint4*)(ppb + (size_t)(h0 + r) * OPLD_ + t0 + cc);
      #pragma unroll
      for (int e = 0; e < 4; ++e) {
        const unsigned int u = (&v.x)[e];
        ppS[(cc + 2 * e) * 20 + r]     = bf2f((unsigned short)(u & 0xffffu));
        ppS[(cc + 2 * e + 1) * 20 + r] = bf2f((unsigned short)(u >> 16));
      }
    }
    __syncthreads();
    float pv[16];
    #pragma unroll
    for (int i = 0; i < 4; ++i) {
      float4 q = *(const float4*)(ppS + tl * 20 + 4 * i);
      pv[4 * i + 0] = q.x; pv[4 * i + 1] = q.y;
      pv[4 * i + 2] = q.z; pv[4 * i + 3] = q.w;
    }
    const int col = tl + 2 * j;
    #pragma unroll
    for (int i = 0; i < 4; ++i) {
      float4 ov = *(const float4*)(opS + col * 20 + 4 * i);
      #pragma unroll
      for (int e = 0; e < 4; ++e) {
        const float r = fmaxf((&ov.x)[e] + pv[4 * i + e], 0.f);
        #pragma unroll
        for (int k = 0; k < 8; ++k) acc[k] += weS[k][h0 + 4 * i + e] * r;
      }
    }
  }
  const int t = t0 + tl;
  float sj = 0.f;
  if (t < TR_) {
    float v[8]; float mx = -1e30f;
    #pragma unroll
    for (int k = 0; k < 8; ++k) {
      v[k] = acc[k] + cvec[k] +
             inner[(((size_t)b * NF_ + j) * NF_ + k) * TR_ + t];
      mx = fmaxf(mx, v[k]);
    }
    float se = 0.f;
    #pragma unroll
    for (int k = 0; k < 8; ++k) se += expf(v[k] - mx);
    sj = v[j] - mx - logf(se);
  }
  #pragma unroll
  for (int off = 32; off > 0; off >>= 1) sj += __shfl_down(sj, off);
  if ((tid & 63) == 0) red[jp] = sj;
  __syncthreads();
  if (tid < 4) {
    const int jw = (jh << 2) + tid;
    part3[(jw * B_ + b) * 32 + blockIdx.x] = red[tid];
  }
}

__global__ void final_out(const float* __restrict__ part3, float* __restrict__ out) {
  const int j = threadIdx.x;
  if (j < NF_) {
    float s = 0.f;
    for (int i = 0; i < B_ * 32; ++i) s += part3[j * B_ * 32 + i];
    out[j] = s / ((float)B_ * (float)TR_);
  }
}

// ---------------------------------------------------------------------------
extern "C" void kernel_launch(void* const* d_in, const int* in_sizes, int n_in,
                              void* d_out, int out_size, void* d_ws, size_t ws_size,
                              hipStream_t stream) {
  const float* predictor = (const float*)d_in[0];
  const float* to_order  = (const float*)d_in[1];
  const float* trilinear = (const float*)d_in[2];
  const float* w_o   = (const float*)d_in[3];
  const float* b_o   = (const float*)d_in[4];
  const float* w_p   = (const float*)d_in[5];
  const float* b_p   = (const float*)d_in[6];
  const float* bn_g  = (const float*)d_in[7];
  const float* bn_b  = (const float*)d_in[8];
  const float* w_out = (const float*)d_in[9];
  const float* b_out = (const float*)d_in[10];
  float* out = (float*)d_out;

  char* w = (char*)d_ws;
  unsigned short* pred_t = (unsigned short*)w; w += (size_t)B_ * T_ * NP_ * 2;
  unsigned short* too_t  = (unsigned short*)w; w += (size_t)B_ * T_ * NO_ * 2;
  unsigned short* tri_bf = (unsigned short*)w; w += (size_t)NF_ * NO_ * NP_ * 2;
  unsigned short* wo_bf  = (unsigned short*)w; w += (size_t)HS_ * NO_ * 2;
  unsigned short* wp_bf  = (unsigned short*)w; w += (size_t)HS_ * NP_ * 2;
  unsigned short* o_proj = (unsigned short*)w; w += (size_t)B_ * HS_ * OPLD_ * 2;
  unsigned short* p_proj = (unsigned short*)w; w += (size_t)B_ * HS_ * OPLD_ * 2;
  float* inner    = (float*)w; w += (size_t)B_ * NF_ * NF_ * TR_ * 4;
  float* partials = (float*)w; w += (size_t)2 * B_ * HS_ * 4;
  float* w_eff    = (float*)w; w += (size_t)NF_ * HS_ * 4;
  float* cvec     = (float*)w; w += 256;
  float* part3    = (float*)w; w += (size_t)NF_ * B_ * 32 * 4;

  transpose_cvt<<<dim3(32, 8, 32), 256, 0, stream>>>(predictor, pred_t,
                                                     to_order, too_t);
  cvt_all<<<2304, 256, 0, stream>>>(trilinear, tri_bf, w_o, wo_bf, w_p, wp_bf);

  proj_mfma<<<dim3(16, 4, 16), 256, 0, stream>>>(
      wo_bf, wp_bf, too_t, pred_t, b_o, b_p, o_proj, p_proj);

  inner_mfma<<<dim3(16, 4, 16), 256, 0, stream>>>(pred_t, too_t, tri_bf, inner);

  bn_stats<<<dim3(HS_, B_), 256, 0, stream>>>(o_proj, p_proj, partials);
  bn_finalize<<<1, 256, 0, stream>>>(partials, bn_g, bn_b, w_out, b_out, w_eff, cvec);
  head_final<<<dim3(32, B_, 2), 256, 0, stream>>>(o_proj, p_proj, w_eff, cvec, inner, part3);
  final_out<<<1, 64, 0, stream>>>(part3, out);
}